// Round 9
// baseline (346.696 us; speedup 1.0000x reference)
//
#include <hip/hip_runtime.h>
#include <hip/hip_bf16.h>
#include <stdint.h>
#include <stddef.h>

typedef unsigned short ushort_t;
typedef unsigned int uint_t;

typedef __attribute__((ext_vector_type(8))) short short8;
typedef __attribute__((ext_vector_type(4))) float floatx4;
typedef __attribute__((ext_vector_type(16))) float floatx16;
typedef __attribute__((ext_vector_type(4))) uint_t uintx4;

#define N_ROWS 32768
#define K_ENT  8192
#define CDIM   256
#define OUT_ELEMS 8388608
#define LOSS_OFF  8388608
#define IDX_OFF   8388609
// Per-(row, k-quarter) survivor list capacity. Measured (r8): single-pass
// running-max appends are ~20 per quarter; CAP_Q=44 puts overflow at ~1e-6.
#define CAP_Q  44
// Margin: covers bf16 rounding of z,c + reference fp32 quantization ulp(256).
// Refine re-filters stored candidates against the FINAL row max (max of stored
// vals), reproducing the two-phase survivor set. Accumulation order (s=0..15
// per tile) is unchanged from R4.
#define MARGIN    2.0e-4f

// RNE float -> bf16 bits
__device__ __forceinline__ ushort_t f2bf(float f) {
    uint_t x = __float_as_uint(f);
    uint_t r = (x + 0x7fffu + ((x >> 16) & 1u)) >> 16;
    return (ushort_t)r;
}

// Swizzled layout for mfma_32x32x16 fragments: element (row, c) lives at
//   (row>>5)*8192 + (c>>4)*512 + ((c>>3)&1)*256 + (row&31)*8 + (c&7)   [ushort idx]
// -> fragment load for k-step s (lane l: row r0+(l&31), dims s*16+(l>>5)*8, 16 B)
//    is one contiguous 1 KiB per (rowgroup, s); a 32-ent tile is 16 KB contiguous
//    and LINEAR -> global_load_lds(16B) staging works with a linear LDS dest.

__device__ __forceinline__ void gload_lds16(const ushort_t* g, ushort_t* s) {
    __builtin_amdgcn_global_load_lds(
        (__attribute__((address_space(1))) void*)(g),
        (__attribute__((address_space(3))) void*)(s), 16, 0, 0);
}

// Fused prep: blocks [0,2048) transpose z -> swizzled bf16 (ztf REMOVED —
// round 9 makes refine ztf-independent); blocks [2048,3072) pack codebook ->
// swizzled bf16, compute per-entry squared norms cn[ent], init acc/cnt2.
__global__ __launch_bounds__(256) void k_prep(const float* __restrict__ zin,
                                              const float* __restrict__ cb,
                                              ushort_t* __restrict__ zsw,
                                              ushort_t* __restrict__ cbsw,
                                              float* __restrict__ cn,
                                              double* __restrict__ acc,
                                              int* __restrict__ cnt2) {
    int bid = blockIdx.x;
    if (bid >= 2048) {
        int t = (bid - 2048) * 256 + threadIdx.x;   // 262,144 items
        if (t == 0) { *acc = 0.0; *cnt2 = 0; }
        int ent = t >> 5;
        int c0  = (t & 31) << 3;
        const float* p = cb + (size_t)ent * CDIM + c0;
        floatx4 f0 = *(const floatx4*)p;
        floatx4 f1 = *(const floatx4*)(p + 4);
        uintx4 pk;
        pk[0] = (uint_t)f2bf(f0[0]) | ((uint_t)f2bf(f0[1]) << 16);
        pk[1] = (uint_t)f2bf(f0[2]) | ((uint_t)f2bf(f0[3]) << 16);
        pk[2] = (uint_t)f2bf(f1[0]) | ((uint_t)f2bf(f1[1]) << 16);
        pk[3] = (uint_t)f2bf(f1[2]) | ((uint_t)f2bf(f1[3]) << 16);
        int idx = (ent >> 5) * 8192 + (c0 >> 4) * 512 + ((c0 >> 3) & 1) * 256 + (ent & 31) * 8;
        *(uintx4*)(cbsw + idx) = pk;
        // entry squared-norm: 8-elem partial + 32-lane-group shuffle reduce
        float pn = 0.f;
#pragma unroll
        for (int qq = 0; qq < 4; ++qq) pn = fmaf(f0[qq], f0[qq], pn);
#pragma unroll
        for (int qq = 0; qq < 4; ++qq) pn = fmaf(f1[qq], f1[qq], pn);
#pragma unroll
        for (int m = 1; m < 32; m <<= 1) pn += __shfl_xor(pn, m);
        if ((t & 31) == 0) cn[ent] = pn;
        return;
    }
    __shared__ float lds[64][65];
    int c0 = (bid & 3) << 6;
    int s0 = ((bid >> 2) & 63) << 6;
    int b  = bid >> 8;
    int tid = threadIdx.x;
    int j = tid & 63, ib = tid >> 6;
    const float* zb = zin + ((size_t)b << 20);
#pragma unroll
    for (int rr = 0; rr < 16; ++rr) {
        int i = rr * 4 + ib;                       // c-local
        lds[i][j] = zb[(size_t)(c0 + i) * 4096 + s0 + j];   // coalesced over j
    }
    __syncthreads();
#pragma unroll
    for (int it = 0; it < 2; ++it) {
        int item = it * 256 + tid;                 // 512 items: (s-local, c-chunk)
        int sl = item >> 3;
        int ch = item & 7;
        int row = (b << 12) + s0 + sl;             // n
        int cg  = c0 + ch * 8;
        uintx4 pk;
#pragma unroll
        for (int q = 0; q < 4; ++q) {
            float a = lds[ch * 8 + 2 * q][sl];
            float bqv = lds[ch * 8 + 2 * q + 1][sl];
            pk[q] = (uint_t)f2bf(a) | ((uint_t)f2bf(bqv) << 16);
        }
        int idx = (row >> 5) * 8192 + (cg >> 4) * 512 + ((cg >> 3) & 1) * 256 + (row & 31) * 8;
        *(uintx4*)(zsw + idx) = pk;
    }
}

// Per-tile max-reduce + survivor append, ATOMIC-FREE + __any skip (R4/R5):
// each (row, quarter) list is written only by lane l and partner l^32 of ONE
// wave; slot allocation in-wave (popc + shfl_xor(32)); cnt written once at
// kernel end. Runs one tile BEHIND the MFMA stream (R7 acc double-buffer).
// C/D layout (32x32x16): col(z-row)=lane&31, ent=(r&3)+8*(r>>2)+4*(l>>5).
__device__ __forceinline__ void screen_emit(const floatx16& acc, float& rmx,
                                            int& cur, int hi, int2* slist,
                                            int ent0) {
    float t0 = fmaxf(fmaxf(acc[0], acc[1]), fmaxf(acc[2], acc[3]));
    float t1 = fmaxf(fmaxf(acc[4], acc[5]), fmaxf(acc[6], acc[7]));
    float t2 = fmaxf(fmaxf(acc[8], acc[9]), fmaxf(acc[10], acc[11]));
    float t3 = fmaxf(fmaxf(acc[12], acc[13]), fmaxf(acc[14], acc[15]));
    float mxo = fmaxf(fmaxf(t0, t1), fmaxf(t2, t3));     // own-16 max
    float mx = fmaxf(mxo, __shfl_xor(mxo, 32));          // full-row tile max
    float rm = fmaxf(rmx, mx);
    rmx = rm;
    float thr = rm - MARGIN;
    if (__any(mxo >= thr)) {
        uint_t mask = 0u;
#pragma unroll
        for (int r = 0; r < 16; ++r)
            if (acc[r] >= thr) mask |= (1u << r);
        int p  = __popc(mask);
        int pp = __shfl_xor(p, 32);       // partner lane's count
        int s  = cur + (hi ? pp : 0);     // low-lane slots first
        cur += p + pp;                    // symmetric -> equal in partners
        if (mask) {
#pragma unroll
            for (int r = 0; r < 16; ++r) {
                if (mask & (1u << r)) {
                    if (s < CAP_Q)
                        slist[s] = make_int2(ent0 + (r & 3) + 8 * (r >> 2),
                                             __float_as_int(acc[r]));
                    ++s;
                }
            }
        }
    }
}

// SINGLE-PASS bf16 MFMA screen — byte-identical to R8 (153 us): 32 rows/wave,
// 1024 blocks, 32 KB dbuf LDS, pipelined emit (accA/accB), persistent zero
// accumulator, running stage pointer.
__global__ __launch_bounds__(256, 4) void k_screen(const ushort_t* __restrict__ zsw,
                                                   const ushort_t* __restrict__ cbsw,
                                                   int2* __restrict__ surv,
                                                   int* __restrict__ cnt) {
    __shared__ ushort_t bt[2][8192];    // 2 x 16 KB B tiles (32 ents each, linear)
    int tid = threadIdx.x;              // 0..255
    int w = tid >> 6, l = tid & 63;
    int bid = blockIdx.x;
    int q  = bid & 3;                   // k-quarter
    int RB = (bid >> 2) * 128;          // row base; wave w owns rows [RB+w*32, +32)
    int n = RB + w * 32 + (l & 31);     // this lane's z-row
    int cidx = n * 4 + q;
    int2* slist = surv + (size_t)cidx * CAP_Q;
    int tile0 = q * 64;                 // first 32-ent tile of this quarter
    int hi = l & 32;

    // running stage pointer: tiles are staged strictly in order 0..63
    const ushort_t* gsp = cbsw + (size_t)tile0 * 8192 + tid * 8;
    auto stage = [&](ushort_t* ld) {    // ld = &bt[buf][w*512]
#pragma unroll
        for (int j = 0; j < 4; ++j)
            gload_lds16(gsp + j * 2048, ld + j * 2048);
        gsp += 8192;                    // next 16 KB tile
    };

    stage(&bt[0][w * 512]);             // tile 0 -> buf 0

    // z fragments (B operand: rows on lanes, 16 k-steps) held in regs all kernel
    short8 zfr[16];
    {
        const ushort_t* pz = zsw + (size_t)((RB >> 5) + w) * 8192 + l * 8;
#pragma unroll
        for (int s = 0; s < 16; ++s)
            zfr[s] = *(const short8*)(pz + s * 512);
    }
    __syncthreads();

    float rmx = -3.0e38f;               // running row max (same in both halves)
    int cur = 0;                        // running survivor count for this row
    int esub = (l >> 5) * 4;            // C/D ent = (r&3) + 8*(r>>2) + 4*(l>>5)

    floatx16 zacc;                      // persistent zero C-input
#pragma unroll
    for (int i = 0; i < 16; ++i) zacc[i] = 0.f;

    floatx16 accA, accB;
    auto compute = [&](floatx16& acc, int b) {
        const ushort_t* bb = &bt[b][l * 8];
        short8 a0 = *(const short8*)(bb);
        acc = __builtin_amdgcn_mfma_f32_32x32x16_bf16(a0, zfr[0], zacc, 0, 0, 0);
#pragma unroll
        for (int s = 1; s < 16; ++s) {
            short8 a = *(const short8*)(bb + s * 512);   // codebook frag (A: ents)
            acc = __builtin_amdgcn_mfma_f32_32x32x16_bf16(a, zfr[s], acc, 0, 0, 0);
        }
    };
    auto ent_of = [&](int t) { return (tile0 + t) * 32 + esub; };

    // t = 0: compute A, nothing to emit yet
    stage(&bt[1][w * 512]);             // tile 1 -> buf 1
    __builtin_amdgcn_s_setprio(1);
    compute(accA, 0);
    __builtin_amdgcn_s_setprio(0);
    __syncthreads();

    for (int t = 1; t < 63; t += 2) {
        // odd tile t: compute B, emit A(t-1) in B's MFMA shadow
        stage(&bt[0][w * 512]);         // tile t+1 (even) -> buf 0
        __builtin_amdgcn_s_setprio(1);
        compute(accB, 1);
        screen_emit(accA, rmx, cur, hi, slist, ent_of(t - 1));
        __builtin_amdgcn_s_setprio(0);
        __syncthreads();
        // even tile t+1: compute A, emit B(t) in A's MFMA shadow
        stage(&bt[1][w * 512]);         // tile t+2 (odd) -> buf 1
        __builtin_amdgcn_s_setprio(1);
        compute(accA, 0);
        screen_emit(accB, rmx, cur, hi, slist, ent_of(t));
        __builtin_amdgcn_s_setprio(0);
        __syncthreads();
    }
    // tail: tile 63 (staged into buf 1 by the last loop iteration)
    __builtin_amdgcn_s_setprio(1);
    compute(accB, 1);
    screen_emit(accA, rmx, cur, hi, slist, ent_of(62));
    __builtin_amdgcn_s_setprio(0);
    screen_emit(accB, rmx, cur, hi, slist, ent_of(63));

    if (!hi) cnt[cidx] = cur;           // one writer per (row, quarter)
}

// ROUND 9: fused refine + gather, ztf-FREE. Block = 64 consecutive rows of one
// batch image. Phase 1: load the z tile COALESCED from the original [b][c][s]
// layout (16 float4/thread, 256 B per 16 lanes) into transposed LDS
// zr[s_local][c] (+1 pad). Phase 2: per wave, 16 rows serially — per-row
// candidate logic IDENTICAL to R8 (same gather order, same serial-fmaf dot,
// same fallback); z served from LDS broadcast. zn uses a lane-tree reduce: zn
// is row-constant and shifts all candidates' u equally -> argmin/tie
// unchanged. Loss per row = bu + cn[bk] (R8 identity). Phase 3: gather cb
// rows -> out via the proven LDS transpose (tile aliases zr); idx never
// round-trips through global. Loss finalized with the proven
// atomicAdd(double) + cnt2 last-block pattern.
__global__ __launch_bounds__(256) void k_refgat(const float* __restrict__ zin,
                                                const float* __restrict__ cb,
                                                const int2* __restrict__ surv,
                                                const int* __restrict__ cnt,
                                                const float* __restrict__ cn,
                                                float* __restrict__ out,
                                                double* __restrict__ acc,
                                                int* __restrict__ cnt2) {
    __shared__ float zr[64][257];       // [s_local][c], pad -> 2-way banks only
    __shared__ int lk[64];
    __shared__ float lossw[4];
    int t = threadIdx.x;
    int wq = t >> 6, l = t & 63;
    int blk = blockIdx.x;
    int b = blk >> 6;
    int s0 = (blk & 63) << 6;
    int n0 = (b << 12) + s0;
    const float* zb = zin + ((size_t)b << 20);

    // phase 1: coalesced tile load + transpose into LDS
#pragma unroll
    for (int k = 0; k < 16; ++k) {
        int item = t + k * 256;         // float4 index in [0, 4096)
        int c = item >> 4;
        int sq = item & 15;
        floatx4 f = *(const floatx4*)(zb + (size_t)c * 4096 + s0 + sq * 4);
#pragma unroll
        for (int j = 0; j < 4; ++j) zr[sq * 4 + j][c] = f[j];
    }
    __syncthreads();

    // phase 2: refine — wave wq owns rows [wq*16, wq*16+16)
    float lsum = 0.f;
    for (int rr = 0; rr < 16; ++rr) {
        int rl = (wq << 4) + rr;
        int n = n0 + rl;
        const float* z = &zr[rl][0];
        float zn = 0.f;
#pragma unroll
        for (int j = 0; j < 4; ++j) { float v = z[l + 64 * j]; zn = fmaf(v, v, zn); }
#pragma unroll
        for (int msk = 1; msk < 64; msk <<= 1) zn += __shfl_xor(zn, msk);

        int q0 = cnt[n * 4 + 0], q1 = cnt[n * 4 + 1];
        int q2 = cnt[n * 4 + 2], q3 = cnt[n * 4 + 3];
        int m = q0 + q1 + q2 + q3;
        bool ok = (q0 <= CAP_Q) && (q1 <= CAP_Q) && (q2 <= CAP_Q) && (q3 <= CAP_Q) && (m >= 1);
        float bu = 3.0e38f;
        int bk = 0x7fffffff;
        if (ok) {
            int myk[3]; float myv[3]; int nc = 0;
            float vmax = -3.0e38f;
            for (int i = l; i < m; i += 64) {
                int qq, s;
                if (i < q0)                { qq = 0; s = i; }
                else if (i < q0 + q1)      { qq = 1; s = i - q0; }
                else if (i < q0 + q1 + q2) { qq = 2; s = i - q0 - q1; }
                else                       { qq = 3; s = i - q0 - q1 - q2; }
                int2 kv = surv[(n * 4 + qq) * CAP_Q + s];
                myk[nc] = kv.x;
                myv[nc] = __int_as_float(kv.y);
                vmax = fmaxf(vmax, myv[nc]);
                ++nc;
            }
#pragma unroll
            for (int msk = 1; msk < 64; msk <<= 1)
                vmax = fmaxf(vmax, __shfl_xor(vmax, msk));
            float fthr = vmax - MARGIN;
            for (int jj = 0; jj < nc; ++jj) {
                if (myv[jj] >= fthr) {
                    int k = myk[jj];
                    const float* cr = cb + (size_t)k * 256;
                    float d = 0.f;
                    for (int c = 0; c < 256; c += 4) {
                        floatx4 cwv = *(const floatx4*)(cr + c);
                        d = fmaf(z[c], cwv[0], d);
                        d = fmaf(z[c + 1], cwv[1], d);
                        d = fmaf(z[c + 2], cwv[2], d);
                        d = fmaf(z[c + 3], cwv[3], d);
                    }
                    float u = zn - 2.0f * d;
                    if (u < bu || (u == bu && k < bk)) { bu = u; bk = k; }
                }
            }
        } else {
            // fallback: exact scan of all K with 4 independent chains (cold path)
            for (int kb = l; kb < K_ENT; kb += 256) {
                const float* p0 = cb + (size_t)(kb)       * 256;
                const float* p1 = cb + (size_t)(kb + 64)  * 256;
                const float* p2 = cb + (size_t)(kb + 128) * 256;
                const float* p3 = cb + (size_t)(kb + 192) * 256;
                float d0 = 0.f, d1 = 0.f, d2 = 0.f, d3 = 0.f;
                for (int c = 0; c < 256; c += 4) {
                    floatx4 w0 = *(const floatx4*)(p0 + c);
                    floatx4 w1 = *(const floatx4*)(p1 + c);
                    floatx4 w2 = *(const floatx4*)(p2 + c);
                    floatx4 w3 = *(const floatx4*)(p3 + c);
#pragma unroll
                    for (int j = 0; j < 4; ++j) {
                        d0 = fmaf(z[c + j], w0[j], d0);
                        d1 = fmaf(z[c + j], w1[j], d1);
                        d2 = fmaf(z[c + j], w2[j], d2);
                        d3 = fmaf(z[c + j], w3[j], d3);
                    }
                }
                float u0 = zn - 2.0f * d0, u1 = zn - 2.0f * d1;
                float u2 = zn - 2.0f * d2, u3 = zn - 2.0f * d3;
                // ascending k order preserves first-index tie-break
                if (u0 < bu) { bu = u0; bk = kb; }
                if (u1 < bu) { bu = u1; bk = kb + 64; }
                if (u2 < bu) { bu = u2; bk = kb + 128; }
                if (u3 < bu) { bu = u3; bk = kb + 192; }
            }
        }
#pragma unroll
        for (int msk = 1; msk < 64; msk <<= 1) {
            float ou = __shfl_xor(bu, msk);
            int   ok2 = __shfl_xor(bk, msk);
            if (ou < bu || (ou == bu && ok2 < bk)) { bu = ou; bk = ok2; }
        }
        if (l == 0) {
            lk[rl] = bk;
            out[IDX_OFF + n] = (float)bk;
            lsum += bu + cn[bk];          // per-row loss = ||c_bk - z||^2
        }
    }
    if (l == 0) lossw[wq] = lsum;
    __syncthreads();                      // lk complete; zr reads done

    // phase 3: gather cb rows -> out (tile aliases zr storage)
    float* tb = &zr[0][0];                // 64 x 65 floats, fits in zr
    float* ob = out + ((size_t)b << 20);
#pragma unroll
    for (int ct = 0; ct < 4; ++ct) {
        int cc0 = ct << 6;
#pragma unroll
        for (int i = 0; i < 16; ++i) {
            int sl = (wq << 4) + i;
            tb[sl * 65 + l] = cb[(size_t)lk[sl] * 256 + cc0 + l];  // 256 B coalesced
        }
        __syncthreads();
#pragma unroll
        for (int j = 0; j < 16; ++j) {
            int cl = (wq << 4) + j;
            ob[(size_t)(cc0 + cl) * 4096 + s0 + l] = tb[l * 65 + cl];
        }
        __syncthreads();
    }

    if (t == 0) {
        float tot = (lossw[0] + lossw[1]) + (lossw[2] + lossw[3]);
        atomicAdd(acc, (double)tot);
        __threadfence();
        int done = atomicAdd(cnt2, 1);
        if (done == (int)gridDim.x - 1) {
            __threadfence();
            double v = atomicAdd(acc, 0.0);   // coherent read after all adds
            out[LOSS_OFF] = (float)(2.0 * v / 8388608.0);
        }
    }
}

extern "C" void kernel_launch(void* const* d_in, const int* in_sizes, int n_in,
                              void* d_out, int out_size, void* d_ws, size_t ws_size,
                              hipStream_t stream) {
    (void)in_sizes; (void)n_in; (void)out_size; (void)ws_size;
    const float* z  = (const float*)d_in[0];
    const float* cb = (const float*)d_in[1];
    float* out = (float*)d_out;
    char* ws = (char*)d_ws;

    size_t off = 0;
    ushort_t* zsw  = (ushort_t*)(ws + off); off += 16777216;   // bf16 swizzled z
    ushort_t* cbsw = (ushort_t*)(ws + off); off += 4194304;    // bf16 swizzled codebook
    const size_t SURV_BYTES = (size_t)N_ROWS * 4 * CAP_Q * 8;   // int2 lists (46 MB)
    int2* surv = (int2*)(ws + off); off += SURV_BYTES;
    int* cnt    = (int*)(ws + off); off += 524288;             // [n][quarter]
    float* cn   = (float*)(ws + off); off += 32768;            // codebook sq-norms
    double* acc = (double*)(ws + off); off += 8;
    int* cnt2   = (int*)(ws + off);

    k_prep<<<3072, 256, 0, stream>>>(z, cb, zsw, cbsw, cn, acc, cnt2);
    k_screen<<<1024, 256, 0, stream>>>(zsw, cbsw, surv, cnt);
    k_refgat<<<512, 256, 0, stream>>>(z, cb, surv, cnt, cn, out, acc, cnt2);
}

// Round 10
// 342.916 us; speedup vs baseline: 1.0110x; 1.0110x over previous
//
#include <hip/hip_runtime.h>
#include <hip/hip_bf16.h>
#include <stdint.h>
#include <stddef.h>

typedef unsigned short ushort_t;
typedef unsigned int uint_t;

typedef __attribute__((ext_vector_type(8))) short short8;
typedef __attribute__((ext_vector_type(4))) float floatx4;
typedef __attribute__((ext_vector_type(16))) float floatx16;
typedef __attribute__((ext_vector_type(4))) uint_t uintx4;

#define N_ROWS 32768
#define K_ENT  8192
#define CDIM   256
#define OUT_ELEMS 8388608
#define LOSS_OFF  8388608
#define IDX_OFF   8388609
// Per-(row, k-quarter) survivor list capacity. Measured (r8): single-pass
// running-max appends are ~20 per quarter; CAP_Q=44 puts overflow at ~1e-6.
// Tile-ring stagger (R10) is a cyclic permutation of the scan order —
// statistically identical append counts.
#define CAP_Q  44
// Margin: covers bf16 rounding of z,c + reference fp32 quantization ulp(256).
// Refine re-filters stored candidates against the FINAL row max (max of stored
// vals), reproducing the two-phase survivor set. Superset property holds for
// ANY tile visit order: within-MARGIN-of-final-max implies within MARGIN of
// every running max -> always stored.
#define MARGIN    2.0e-4f

// RNE float -> bf16 bits
__device__ __forceinline__ ushort_t f2bf(float f) {
    uint_t x = __float_as_uint(f);
    uint_t r = (x + 0x7fffu + ((x >> 16) & 1u)) >> 16;
    return (ushort_t)r;
}

// Swizzled layout for mfma_32x32x16 fragments: element (row, c) lives at
//   (row>>5)*8192 + (c>>4)*512 + ((c>>3)&1)*256 + (row&31)*8 + (c&7)   [ushort idx]
// -> fragment load for k-step s (lane l: row r0+(l&31), dims s*16+(l>>5)*8, 16 B)
//    is one contiguous 1 KiB per (rowgroup, s); a 32-ent tile is 16 KB contiguous
//    and LINEAR -> global_load_lds(16B) staging works with a linear LDS dest.

__device__ __forceinline__ void gload_lds16(const ushort_t* g, ushort_t* s) {
    __builtin_amdgcn_global_load_lds(
        (__attribute__((address_space(1))) void*)(g),
        (__attribute__((address_space(3))) void*)(s), 16, 0, 0);
}

// Fused prep: blocks [0,2048) transpose z -> swizzled bf16 (+ fp32 ztf copy);
// blocks [2048,3072) pack codebook -> swizzled bf16 AND compute per-entry
// squared norms cn[ent] (used by refine's loss: ||c-z||^2 = cn + (zn - 2d)).
__global__ __launch_bounds__(256) void k_prep(const float* __restrict__ zin,
                                              const float* __restrict__ cb,
                                              ushort_t* __restrict__ zsw,
                                              ushort_t* __restrict__ cbsw,
                                              float* __restrict__ ztf,
                                              float* __restrict__ cn) {
    int bid = blockIdx.x;
    if (bid >= 2048) {
        int t = (bid - 2048) * 256 + threadIdx.x;   // 262,144 items
        int ent = t >> 5;
        int c0  = (t & 31) << 3;
        const float* p = cb + (size_t)ent * CDIM + c0;
        floatx4 f0 = *(const floatx4*)p;
        floatx4 f1 = *(const floatx4*)(p + 4);
        uintx4 pk;
        pk[0] = (uint_t)f2bf(f0[0]) | ((uint_t)f2bf(f0[1]) << 16);
        pk[1] = (uint_t)f2bf(f0[2]) | ((uint_t)f2bf(f0[3]) << 16);
        pk[2] = (uint_t)f2bf(f1[0]) | ((uint_t)f2bf(f1[1]) << 16);
        pk[3] = (uint_t)f2bf(f1[2]) | ((uint_t)f2bf(f1[3]) << 16);
        int idx = (ent >> 5) * 8192 + (c0 >> 4) * 512 + ((c0 >> 3) & 1) * 256 + (ent & 31) * 8;
        *(uintx4*)(cbsw + idx) = pk;
        // entry squared-norm: 8-elem partial + 32-lane-group shuffle reduce
        float pn = 0.f;
#pragma unroll
        for (int qq = 0; qq < 4; ++qq) pn = fmaf(f0[qq], f0[qq], pn);
#pragma unroll
        for (int qq = 0; qq < 4; ++qq) pn = fmaf(f1[qq], f1[qq], pn);
#pragma unroll
        for (int m = 1; m < 32; m <<= 1) pn += __shfl_xor(pn, m);
        if ((t & 31) == 0) cn[ent] = pn;
        return;
    }
    __shared__ float lds[64][65];
    int c0 = (bid & 3) << 6;
    int s0 = ((bid >> 2) & 63) << 6;
    int b  = bid >> 8;
    int tid = threadIdx.x;
    int j = tid & 63, ib = tid >> 6;
    const float* zb = zin + ((size_t)b << 20);
#pragma unroll
    for (int rr = 0; rr < 16; ++rr) {
        int i = rr * 4 + ib;                       // c-local
        lds[i][j] = zb[(size_t)(c0 + i) * 4096 + s0 + j];   // coalesced over j
    }
    __syncthreads();
#pragma unroll
    for (int it = 0; it < 2; ++it) {
        int item = it * 256 + tid;                 // 512 items: (s-local, c-chunk)
        int sl = item >> 3;
        int ch = item & 7;
        int row = (b << 12) + s0 + sl;             // n
        int cg  = c0 + ch * 8;
        uintx4 pk;
        floatx4 f0, f1;
#pragma unroll
        for (int q = 0; q < 4; ++q) {
            float a = lds[ch * 8 + 2 * q][sl];
            float bqv = lds[ch * 8 + 2 * q + 1][sl];
            pk[q] = (uint_t)f2bf(a) | ((uint_t)f2bf(bqv) << 16);
        }
#pragma unroll
        for (int q = 0; q < 4; ++q) {
            f0[q] = lds[ch * 8 + q][sl];
            f1[q] = lds[ch * 8 + 4 + q][sl];
        }
        int idx = (row >> 5) * 8192 + (cg >> 4) * 512 + ((cg >> 3) & 1) * 256 + (row & 31) * 8;
        *(uintx4*)(zsw + idx) = pk;
        if (ztf) {
            *(floatx4*)(ztf + (size_t)row * 256 + cg) = f0;
            *(floatx4*)(ztf + (size_t)row * 256 + cg + 4) = f1;
        }
    }
}

// Per-tile max-reduce + survivor append, ATOMIC-FREE + __any skip (R4/R5):
// each (row, quarter) list is written only by lane l and partner l^32 of ONE
// wave; slot allocation in-wave (popc + shfl_xor(32)); cnt written once at
// kernel end. Runs one tile BEHIND the MFMA stream (R7 acc double-buffer).
// C/D layout (32x32x16): col(z-row)=lane&31, ent=(r&3)+8*(r>>2)+4*(l>>5).
__device__ __forceinline__ void screen_emit(const floatx16& acc, float& rmx,
                                            int& cur, int hi, int2* slist,
                                            int ent0) {
    float t0 = fmaxf(fmaxf(acc[0], acc[1]), fmaxf(acc[2], acc[3]));
    float t1 = fmaxf(fmaxf(acc[4], acc[5]), fmaxf(acc[6], acc[7]));
    float t2 = fmaxf(fmaxf(acc[8], acc[9]), fmaxf(acc[10], acc[11]));
    float t3 = fmaxf(fmaxf(acc[12], acc[13]), fmaxf(acc[14], acc[15]));
    float mxo = fmaxf(fmaxf(t0, t1), fmaxf(t2, t3));     // own-16 max
    float mx = fmaxf(mxo, __shfl_xor(mxo, 32));          // full-row tile max
    float rm = fmaxf(rmx, mx);
    rmx = rm;
    float thr = rm - MARGIN;
    if (__any(mxo >= thr)) {
        uint_t mask = 0u;
#pragma unroll
        for (int r = 0; r < 16; ++r)
            if (acc[r] >= thr) mask |= (1u << r);
        int p  = __popc(mask);
        int pp = __shfl_xor(p, 32);       // partner lane's count
        int s  = cur + (hi ? pp : 0);     // low-lane slots first
        cur += p + pp;                    // symmetric -> equal in partners
        if (mask) {
#pragma unroll
            for (int r = 0; r < 16; ++r) {
                if (mask & (1u << r)) {
                    if (s < CAP_Q)
                        slist[s] = make_int2(ent0 + (r & 3) + 8 * (r >> 2),
                                             __float_as_int(acc[r]));
                    ++s;
                }
            }
        }
    }
}

// SINGLE-PASS bf16 MFMA screen — R8 structure + ROUND 10 TILE-RING STAGGER.
// All 1024 blocks previously walked tiles 0..63 in the same order and
// self-synchronized through DS/L2 contention (convoy: DS pipe idle while all
// resident waves sit in MFMA/emit/barrier together -> measured 53% DS util).
// Now block with quarter-rank j starts at tile (j & 63) and walks the ring
// (toff + t) & 63 — co-resident blocks occupy decorrelated phases. Survivor
// semantics are order-independent (superset property + value-based re-filter
// in refine); append counts are a cyclic permutation (CAP_Q unchanged).
__global__ __launch_bounds__(256, 4) void k_screen(const ushort_t* __restrict__ zsw,
                                                   const ushort_t* __restrict__ cbsw,
                                                   int2* __restrict__ surv,
                                                   int* __restrict__ cnt) {
    __shared__ ushort_t bt[2][8192];    // 2 x 16 KB B tiles (32 ents each, linear)
    int tid = threadIdx.x;              // 0..255
    int w = tid >> 6, l = tid & 63;
    int bid = blockIdx.x;
    int q  = bid & 3;                   // k-quarter
    int RB = (bid >> 2) * 128;          // row base; wave w owns rows [RB+w*32, +32)
    int n = RB + w * 32 + (l & 31);     // this lane's z-row
    int cidx = n * 4 + q;
    int2* slist = surv + (size_t)cidx * CAP_Q;
    int tile0 = q * 64;                 // first 32-ent tile of this quarter
    int hi = l & 32;
    int toff = (bid >> 2) & 63;         // tile-ring start offset (stagger)

    // stage the next ring tile into the given buffer (16 KB = 256 thr x 16 B x 4)
    const ushort_t* gqb = cbsw + (size_t)tile0 * 8192 + tid * 8;  // quarter base
    int stg = toff;                     // next physical tile to stage
    auto stage = [&](ushort_t* ld) {    // ld = &bt[buf][w*512]
        const ushort_t* gs = gqb + (size_t)stg * 8192;
#pragma unroll
        for (int j = 0; j < 4; ++j)
            gload_lds16(gs + j * 2048, ld + j * 2048);
        stg = (stg + 1) & 63;
    };

    stage(&bt[0][w * 512]);             // ring tile 0 -> buf 0

    // z fragments (B operand: rows on lanes, 16 k-steps) held in regs all kernel
    short8 zfr[16];
    {
        const ushort_t* pz = zsw + (size_t)((RB >> 5) + w) * 8192 + l * 8;
#pragma unroll
        for (int s = 0; s < 16; ++s)
            zfr[s] = *(const short8*)(pz + s * 512);
    }
    __syncthreads();

    float rmx = -3.0e38f;               // running row max (same in both halves)
    int cur = 0;                        // running survivor count for this row
    int esub = (l >> 5) * 4;            // C/D ent = (r&3) + 8*(r>>2) + 4*(l>>5)

    floatx16 zacc;                      // persistent zero C-input
#pragma unroll
    for (int i = 0; i < 16; ++i) zacc[i] = 0.f;

    floatx16 accA, accB;
    auto compute = [&](floatx16& acc, int b) {
        const ushort_t* bb = &bt[b][l * 8];
        short8 a0 = *(const short8*)(bb);
        acc = __builtin_amdgcn_mfma_f32_32x32x16_bf16(a0, zfr[0], zacc, 0, 0, 0);
#pragma unroll
        for (int s = 1; s < 16; ++s) {
            short8 a = *(const short8*)(bb + s * 512);   // codebook frag (A: ents)
            acc = __builtin_amdgcn_mfma_f32_32x32x16_bf16(a, zfr[s], acc, 0, 0, 0);
        }
    };
    auto ent_of = [&](int t) { return (tile0 + ((toff + t) & 63)) * 32 + esub; };

    // t = 0: compute A, nothing to emit yet
    stage(&bt[1][w * 512]);             // ring tile 1 -> buf 1
    __builtin_amdgcn_s_setprio(1);
    compute(accA, 0);
    __builtin_amdgcn_s_setprio(0);
    __syncthreads();

    for (int t = 1; t < 63; t += 2) {
        // ring tile t: compute B, emit A(t-1) in B's MFMA shadow
        stage(&bt[0][w * 512]);         // ring tile t+1 -> buf 0
        __builtin_amdgcn_s_setprio(1);
        compute(accB, 1);
        screen_emit(accA, rmx, cur, hi, slist, ent_of(t - 1));
        __builtin_amdgcn_s_setprio(0);
        __syncthreads();
        // ring tile t+1: compute A, emit B(t) in A's MFMA shadow
        stage(&bt[1][w * 512]);         // ring tile t+2 -> buf 1
        __builtin_amdgcn_s_setprio(1);
        compute(accA, 0);
        screen_emit(accB, rmx, cur, hi, slist, ent_of(t));
        __builtin_amdgcn_s_setprio(0);
        __syncthreads();
    }
    // tail: ring tile 63 (staged into buf 1 by the last loop iteration)
    __builtin_amdgcn_s_setprio(1);
    compute(accB, 1);
    screen_emit(accA, rmx, cur, hi, slist, ent_of(62));
    __builtin_amdgcn_s_setprio(0);
    screen_emit(accB, rmx, cur, hi, slist, ent_of(63));

    if (!hi) cnt[cidx] = cur;           // one writer per (row, quarter)
}

// Exact fp32 refine: gather <=176 stored (ent, bf16-dot) candidates from the 4
// quarter lists, filter by val >= finalmax - MARGIN (finalmax = max stored val;
// the record-setter always self-appends), then fp32 dots for the ~1-3 passing
// candidates. Serial fmaf order unchanged, so idx semantics are unchanged.
// Emits per-block loss partial: per-row loss = cn[bk] + bu (bu = zn - 2d of
// the winner). zn shifts all u_k equally -> argmin/tie semantics untouched.
__global__ __launch_bounds__(256) void k_refine(const float* __restrict__ zin,
                                                const float* __restrict__ ztf,
                                                const float* __restrict__ cb,
                                                const int2* __restrict__ surv,
                                                const int* __restrict__ cnt,
                                                int* __restrict__ idxi,
                                                float* __restrict__ idxf,
                                                const float* __restrict__ cn,
                                                float* __restrict__ lossp) {
    __shared__ float zr[4][256];
    __shared__ float lossw[4];
    int w = threadIdx.x >> 6, l = threadIdx.x & 63;
    int n = blockIdx.x * 4 + w;
    if (ztf) {
        const float* zrow = ztf + (size_t)n * 256;
#pragma unroll
        for (int i = 0; i < 4; ++i)
            zr[w][l + 64 * i] = zrow[l + 64 * i];          // coalesced
    } else {
        int b = n >> 12, s = n & 4095;
        const float* zb = zin + ((size_t)b << 20) + s;
#pragma unroll
        for (int i = 0; i < 4; ++i)
            zr[w][l + 64 * i] = zb[(size_t)(l + 64 * i) << 12];
    }
    __syncthreads();
    const float* z = zr[w];
    float zn = 0.f;
    for (int c = 0; c < 256; ++c) zn = fmaf(z[c], z[c], zn);

    int c0 = cnt[n * 4 + 0], c1 = cnt[n * 4 + 1];
    int c2 = cnt[n * 4 + 2], c3 = cnt[n * 4 + 3];
    int m = c0 + c1 + c2 + c3;
    bool ok = (c0 <= CAP_Q) && (c1 <= CAP_Q) && (c2 <= CAP_Q) && (c3 <= CAP_Q) && (m >= 1);
    float bu = 3.0e38f;
    int bk = 0x7fffffff;
    if (ok) {
        int myk[3]; float myv[3]; int nc = 0;
        float vmax = -3.0e38f;
        for (int i = l; i < m; i += 64) {
            int qq, s;
            if (i < c0)            { qq = 0; s = i; }
            else if (i < c0 + c1)  { qq = 1; s = i - c0; }
            else if (i < c0 + c1 + c2) { qq = 2; s = i - c0 - c1; }
            else                   { qq = 3; s = i - c0 - c1 - c2; }
            int2 kv = surv[(n * 4 + qq) * CAP_Q + s];
            myk[nc] = kv.x;
            myv[nc] = __int_as_float(kv.y);
            vmax = fmaxf(vmax, myv[nc]);
            ++nc;
        }
#pragma unroll
        for (int msk = 1; msk < 64; msk <<= 1)
            vmax = fmaxf(vmax, __shfl_xor(vmax, msk));
        float fthr = vmax - MARGIN;
        for (int jj = 0; jj < nc; ++jj) {
            if (myv[jj] >= fthr) {
                int k = myk[jj];
                const float* cr = cb + (size_t)k * 256;
                float d = 0.f;
                for (int c = 0; c < 256; c += 4) {
                    floatx4 wv = *(const floatx4*)(cr + c);
                    d = fmaf(z[c], wv[0], d);
                    d = fmaf(z[c + 1], wv[1], d);
                    d = fmaf(z[c + 2], wv[2], d);
                    d = fmaf(z[c + 3], wv[3], d);
                }
                float u = zn - 2.0f * d;
                if (u < bu || (u == bu && k < bk)) { bu = u; bk = k; }
            }
        }
    } else {
        // fallback: exact scan of all K with 4 independent chains (cold path)
        for (int kb = l; kb < K_ENT; kb += 256) {
            const float* p0 = cb + (size_t)(kb)       * 256;
            const float* p1 = cb + (size_t)(kb + 64)  * 256;
            const float* p2 = cb + (size_t)(kb + 128) * 256;
            const float* p3 = cb + (size_t)(kb + 192) * 256;
            float d0 = 0.f, d1 = 0.f, d2 = 0.f, d3 = 0.f;
            for (int c = 0; c < 256; c += 4) {
                floatx4 w0 = *(const floatx4*)(p0 + c);
                floatx4 w1 = *(const floatx4*)(p1 + c);
                floatx4 w2 = *(const floatx4*)(p2 + c);
                floatx4 w3 = *(const floatx4*)(p3 + c);
#pragma unroll
                for (int j = 0; j < 4; ++j) {
                    d0 = fmaf(z[c + j], w0[j], d0);
                    d1 = fmaf(z[c + j], w1[j], d1);
                    d2 = fmaf(z[c + j], w2[j], d2);
                    d3 = fmaf(z[c + j], w3[j], d3);
                }
            }
            float u0 = zn - 2.0f * d0, u1 = zn - 2.0f * d1;
            float u2 = zn - 2.0f * d2, u3 = zn - 2.0f * d3;
            // ascending k order preserves first-index tie-break
            if (u0 < bu) { bu = u0; bk = kb; }
            if (u1 < bu) { bu = u1; bk = kb + 64; }
            if (u2 < bu) { bu = u2; bk = kb + 128; }
            if (u3 < bu) { bu = u3; bk = kb + 192; }
        }
    }
#pragma unroll
    for (int msk = 1; msk < 64; msk <<= 1) {
        float ou = __shfl_xor(bu, msk);
        int   ok2 = __shfl_xor(bk, msk);
        if (ou < bu || (ou == bu && ok2 < bk)) { bu = ou; bk = ok2; }
    }
    if (l == 0) {
        idxi[n] = bk;
        idxf[n] = (float)bk;
        lossw[w] = bu + cn[bk];          // per-row loss = ||c_bk - z||^2
    }
    __syncthreads();
    if (threadIdx.x == 0)
        lossp[blockIdx.x] = (lossw[0] + lossw[1]) + (lossw[2] + lossw[3]);
}

// Gather z_q (coalesced codebook reads via LDS transpose): pure gather-scatter;
// block 0 additionally sums the 8192 refine loss partials in double and writes
// the final loss (no atomics / fences / completion counter).
__global__ __launch_bounds__(256) void k_gather(const float* __restrict__ cb,
                                                const int* __restrict__ idxi,
                                                const float* __restrict__ lossp,
                                                float* __restrict__ out) {
    __shared__ float tile[64][65];
    __shared__ int lk[64];
    __shared__ double dsum[4];
    int t = threadIdx.x;
    int blk = blockIdx.x;
    int b = blk >> 6;
    int s0 = (blk & 63) << 6;
    int n0 = (b << 12) + s0;
    if (t < 64) lk[t] = idxi[n0 + t];
    __syncthreads();
    int wv = t >> 6, ln = t & 63;
    float* ob = out + ((size_t)b << 20);
#pragma unroll
    for (int ct = 0; ct < 4; ++ct) {
        int c0 = ct << 6;
#pragma unroll
        for (int i = 0; i < 16; ++i) {
            int sl = (wv << 4) + i;
            tile[sl][ln] = cb[(size_t)lk[sl] * 256 + c0 + ln];   // 256 B coalesced
        }
        __syncthreads();
#pragma unroll
        for (int j = 0; j < 16; ++j) {
            int cl = (wv << 4) + j;
            ob[(size_t)(c0 + cl) * 4096 + s0 + ln] = tile[ln][cl];
        }
        __syncthreads();
    }
    if (blk == 0) {
        double s = 0.0;
        for (int i = t; i < 8192; i += 256) s += (double)lossp[i];
#pragma unroll
        for (int msk = 1; msk < 64; msk <<= 1) s += __shfl_xor(s, msk);
        if (ln == 0) dsum[wv] = s;
        __syncthreads();
        if (t == 0)
            out[LOSS_OFF] = (float)(2.0 * ((dsum[0] + dsum[1]) + (dsum[2] + dsum[3]))
                                    / 8388608.0);
    }
}

extern "C" void kernel_launch(void* const* d_in, const int* in_sizes, int n_in,
                              void* d_out, int out_size, void* d_ws, size_t ws_size,
                              hipStream_t stream) {
    (void)in_sizes; (void)n_in; (void)out_size;
    const float* z  = (const float*)d_in[0];
    const float* cb = (const float*)d_in[1];
    float* out = (float*)d_out;
    char* ws = (char*)d_ws;

    size_t off = 0;
    ushort_t* zsw  = (ushort_t*)(ws + off); off += 16777216;   // bf16 swizzled z
    ushort_t* cbsw = (ushort_t*)(ws + off); off += 4194304;    // bf16 swizzled codebook
    float* ztf = nullptr;
    const size_t ZTF_BYTES = 33554432;                          // fp32 transposed z
    const size_t SURV_BYTES = (size_t)N_ROWS * 4 * CAP_Q * 8;   // int2 lists (46 MB)
    const size_t TAIL = SURV_BYTES + 524288 + 131072 + 32768 + 32768;
    if (ws_size >= off + ZTF_BYTES + TAIL) { ztf = (float*)(ws + off); off += ZTF_BYTES; }
    int2* surv = (int2*)(ws + off); off += SURV_BYTES;
    int* cnt    = (int*)(ws + off); off += 524288;             // [n][quarter]
    int* idxi   = (int*)(ws + off); off += 131072;
    float* cn   = (float*)(ws + off); off += 32768;            // codebook sq-norms
    float* lossp = (float*)(ws + off); off += 32768;           // per-refine-block loss

    k_prep<<<3072, 256, 0, stream>>>(z, cb, zsw, cbsw, ztf, cn);
    k_screen<<<1024, 256, 0, stream>>>(zsw, cbsw, surv, cnt);
    k_refine<<<8192, 256, 0, stream>>>(z, ztf, cb, surv, cnt, idxi, out + IDX_OFF, cn, lossp);
    k_gather<<<8192 / 16, 256, 0, stream>>>(cb, idxi, lossp, out);
}

// Round 11
// 337.915 us; speedup vs baseline: 1.0260x; 1.0148x over previous
//
#include <hip/hip_runtime.h>
#include <hip/hip_bf16.h>
#include <stdint.h>
#include <stddef.h>

typedef unsigned short ushort_t;
typedef unsigned int uint_t;

typedef __attribute__((ext_vector_type(8))) short short8;
typedef __attribute__((ext_vector_type(4))) float floatx4;
typedef __attribute__((ext_vector_type(16))) float floatx16;
typedef __attribute__((ext_vector_type(4))) uint_t uintx4;

#define N_ROWS 32768
#define K_ENT  8192
#define CDIM   256
#define OUT_ELEMS 8388608
#define LOSS_OFF  8388608
#define IDX_OFF   8388609
// Per-(row, k-quarter) survivor list capacity. Measured (r8): single-pass
// running-max appends are ~20 per quarter; CAP_Q=44 puts overflow at ~1e-6.
#define CAP_Q  44
// Margin: covers bf16 rounding of z,c + reference fp32 quantization ulp(256).
// Refine re-filters stored candidates against the FINAL row max (max of stored
// vals), reproducing the two-phase survivor set. Accumulation order (s=0..15
// per tile) is unchanged from R4.
#define MARGIN    2.0e-4f

// RNE float -> bf16 bits
__device__ __forceinline__ ushort_t f2bf(float f) {
    uint_t x = __float_as_uint(f);
    uint_t r = (x + 0x7fffu + ((x >> 16) & 1u)) >> 16;
    return (ushort_t)r;
}

// Swizzled layout for mfma_32x32x16 fragments: element (row, c) lives at
//   (row>>5)*8192 + (c>>4)*512 + ((c>>3)&1)*256 + (row&31)*8 + (c&7)   [ushort idx]
// -> fragment load for k-step s (lane l: row r0+(l&31), dims s*16+(l>>5)*8, 16 B)
//    is one contiguous 1 KiB per (rowgroup, s); a 32-ent tile is 16 KB contiguous
//    and LINEAR -> global_load_lds(16B) staging works with a linear LDS dest.
// NOTE (R10 lesson): all blocks of a quarter walk tiles 0..63 in the SAME
// order on purpose — simultaneous same-tile reads hit L2 on each other's
// fetches. Staggering the order cost 5% and +2.3 MB FETCH.

__device__ __forceinline__ void gload_lds16(const ushort_t* g, ushort_t* s) {
    __builtin_amdgcn_global_load_lds(
        (__attribute__((address_space(1))) void*)(g),
        (__attribute__((address_space(3))) void*)(s), 16, 0, 0);
}

// Fused prep: blocks [0,2048) transpose z -> swizzled bf16 (+ fp32 ztf copy);
// blocks [2048,3072) pack codebook -> swizzled bf16 AND compute per-entry
// squared norms cn[ent] (used by refine's loss: ||c-z||^2 = cn + (zn - 2d)).
__global__ __launch_bounds__(256) void k_prep(const float* __restrict__ zin,
                                              const float* __restrict__ cb,
                                              ushort_t* __restrict__ zsw,
                                              ushort_t* __restrict__ cbsw,
                                              float* __restrict__ ztf,
                                              float* __restrict__ cn) {
    int bid = blockIdx.x;
    if (bid >= 2048) {
        int t = (bid - 2048) * 256 + threadIdx.x;   // 262,144 items
        int ent = t >> 5;
        int c0  = (t & 31) << 3;
        const float* p = cb + (size_t)ent * CDIM + c0;
        floatx4 f0 = *(const floatx4*)p;
        floatx4 f1 = *(const floatx4*)(p + 4);
        uintx4 pk;
        pk[0] = (uint_t)f2bf(f0[0]) | ((uint_t)f2bf(f0[1]) << 16);
        pk[1] = (uint_t)f2bf(f0[2]) | ((uint_t)f2bf(f0[3]) << 16);
        pk[2] = (uint_t)f2bf(f1[0]) | ((uint_t)f2bf(f1[1]) << 16);
        pk[3] = (uint_t)f2bf(f1[2]) | ((uint_t)f2bf(f1[3]) << 16);
        int idx = (ent >> 5) * 8192 + (c0 >> 4) * 512 + ((c0 >> 3) & 1) * 256 + (ent & 31) * 8;
        *(uintx4*)(cbsw + idx) = pk;
        // entry squared-norm: 8-elem partial + 32-lane-group shuffle reduce
        float pn = 0.f;
#pragma unroll
        for (int qq = 0; qq < 4; ++qq) pn = fmaf(f0[qq], f0[qq], pn);
#pragma unroll
        for (int qq = 0; qq < 4; ++qq) pn = fmaf(f1[qq], f1[qq], pn);
#pragma unroll
        for (int m = 1; m < 32; m <<= 1) pn += __shfl_xor(pn, m);
        if ((t & 31) == 0) cn[ent] = pn;
        return;
    }
    __shared__ float lds[64][65];
    int c0 = (bid & 3) << 6;
    int s0 = ((bid >> 2) & 63) << 6;
    int b  = bid >> 8;
    int tid = threadIdx.x;
    int j = tid & 63, ib = tid >> 6;
    const float* zb = zin + ((size_t)b << 20);
#pragma unroll
    for (int rr = 0; rr < 16; ++rr) {
        int i = rr * 4 + ib;                       // c-local
        lds[i][j] = zb[(size_t)(c0 + i) * 4096 + s0 + j];   // coalesced over j
    }
    __syncthreads();
#pragma unroll
    for (int it = 0; it < 2; ++it) {
        int item = it * 256 + tid;                 // 512 items: (s-local, c-chunk)
        int sl = item >> 3;
        int ch = item & 7;
        int row = (b << 12) + s0 + sl;             // n
        int cg  = c0 + ch * 8;
        uintx4 pk;
        floatx4 f0, f1;
#pragma unroll
        for (int q = 0; q < 4; ++q) {
            float a = lds[ch * 8 + 2 * q][sl];
            float bqv = lds[ch * 8 + 2 * q + 1][sl];
            pk[q] = (uint_t)f2bf(a) | ((uint_t)f2bf(bqv) << 16);
        }
#pragma unroll
        for (int q = 0; q < 4; ++q) {
            f0[q] = lds[ch * 8 + q][sl];
            f1[q] = lds[ch * 8 + 4 + q][sl];
        }
        int idx = (row >> 5) * 8192 + (cg >> 4) * 512 + ((cg >> 3) & 1) * 256 + (row & 31) * 8;
        *(uintx4*)(zsw + idx) = pk;
        if (ztf) {
            *(floatx4*)(ztf + (size_t)row * 256 + cg) = f0;
            *(floatx4*)(ztf + (size_t)row * 256 + cg + 4) = f1;
        }
    }
}

// Per-tile max-reduce + survivor append, ATOMIC-FREE + __any skip (R4/R5):
// each (row, quarter) list is written only by lane l and partner l^32 of ONE
// wave; slot allocation in-wave (popc + shfl_xor(32)); cnt written once at
// kernel end. Runs one tile BEHIND the MFMA stream (R7 acc double-buffer).
// C/D layout (32x32x16): col(z-row)=lane&31, ent=(r&3)+8*(r>>2)+4*(l>>5).
__device__ __forceinline__ void screen_emit(const floatx16& acc, float& rmx,
                                            int& cur, int hi, int2* slist,
                                            int ent0) {
    float t0 = fmaxf(fmaxf(acc[0], acc[1]), fmaxf(acc[2], acc[3]));
    float t1 = fmaxf(fmaxf(acc[4], acc[5]), fmaxf(acc[6], acc[7]));
    float t2 = fmaxf(fmaxf(acc[8], acc[9]), fmaxf(acc[10], acc[11]));
    float t3 = fmaxf(fmaxf(acc[12], acc[13]), fmaxf(acc[14], acc[15]));
    float mxo = fmaxf(fmaxf(t0, t1), fmaxf(t2, t3));     // own-16 max
    float mx = fmaxf(mxo, __shfl_xor(mxo, 32));          // full-row tile max
    float rm = fmaxf(rmx, mx);
    rmx = rm;
    float thr = rm - MARGIN;
    if (__any(mxo >= thr)) {
        uint_t mask = 0u;
#pragma unroll
        for (int r = 0; r < 16; ++r)
            if (acc[r] >= thr) mask |= (1u << r);
        int p  = __popc(mask);
        int pp = __shfl_xor(p, 32);       // partner lane's count
        int s  = cur + (hi ? pp : 0);     // low-lane slots first
        cur += p + pp;                    // symmetric -> equal in partners
        if (mask) {
#pragma unroll
            for (int r = 0; r < 16; ++r) {
                if (mask & (1u << r)) {
                    if (s < CAP_Q)
                        slist[s] = make_int2(ent0 + (r & 3) + 8 * (r >> 2),
                                             __float_as_int(acc[r]));
                    ++s;
                }
            }
        }
    }
}

// SINGLE-PASS bf16 MFMA screen — R8 byte-exact (best measured: 153.5 us).
// 32 rows/wave, 1024 blocks, 32 KB dbuf LDS, sequential tile walk (L2
// co-read locality), pipelined emit (accA/accB), persistent zero accumulator,
// running stage pointer.
__global__ __launch_bounds__(256, 4) void k_screen(const ushort_t* __restrict__ zsw,
                                                   const ushort_t* __restrict__ cbsw,
                                                   int2* __restrict__ surv,
                                                   int* __restrict__ cnt) {
    __shared__ ushort_t bt[2][8192];    // 2 x 16 KB B tiles (32 ents each, linear)
    int tid = threadIdx.x;              // 0..255
    int w = tid >> 6, l = tid & 63;
    int bid = blockIdx.x;
    int q  = bid & 3;                   // k-quarter
    int RB = (bid >> 2) * 128;          // row base; wave w owns rows [RB+w*32, +32)
    int n = RB + w * 32 + (l & 31);     // this lane's z-row
    int cidx = n * 4 + q;
    int2* slist = surv + (size_t)cidx * CAP_Q;
    int tile0 = q * 64;                 // first 32-ent tile of this quarter
    int hi = l & 32;

    // running stage pointer: tiles are staged strictly in order 0..63
    const ushort_t* gsp = cbsw + (size_t)tile0 * 8192 + tid * 8;
    auto stage = [&](ushort_t* ld) {    // ld = &bt[buf][w*512]
#pragma unroll
        for (int j = 0; j < 4; ++j)
            gload_lds16(gsp + j * 2048, ld + j * 2048);
        gsp += 8192;                    // next 16 KB tile
    };

    stage(&bt[0][w * 512]);             // tile 0 -> buf 0

    // z fragments (B operand: rows on lanes, 16 k-steps) held in regs all kernel
    short8 zfr[16];
    {
        const ushort_t* pz = zsw + (size_t)((RB >> 5) + w) * 8192 + l * 8;
#pragma unroll
        for (int s = 0; s < 16; ++s)
            zfr[s] = *(const short8*)(pz + s * 512);
    }
    __syncthreads();

    float rmx = -3.0e38f;               // running row max (same in both halves)
    int cur = 0;                        // running survivor count for this row
    int esub = (l >> 5) * 4;            // C/D ent = (r&3) + 8*(r>>2) + 4*(l>>5)

    floatx16 zacc;                      // persistent zero C-input
#pragma unroll
    for (int i = 0; i < 16; ++i) zacc[i] = 0.f;

    floatx16 accA, accB;
    auto compute = [&](floatx16& acc, int b) {
        const ushort_t* bb = &bt[b][l * 8];
        short8 a0 = *(const short8*)(bb);
        acc = __builtin_amdgcn_mfma_f32_32x32x16_bf16(a0, zfr[0], zacc, 0, 0, 0);
#pragma unroll
        for (int s = 1; s < 16; ++s) {
            short8 a = *(const short8*)(bb + s * 512);   // codebook frag (A: ents)
            acc = __builtin_amdgcn_mfma_f32_32x32x16_bf16(a, zfr[s], acc, 0, 0, 0);
        }
    };
    auto ent_of = [&](int t) { return (tile0 + t) * 32 + esub; };

    // t = 0: compute A, nothing to emit yet
    stage(&bt[1][w * 512]);             // tile 1 -> buf 1
    __builtin_amdgcn_s_setprio(1);
    compute(accA, 0);
    __builtin_amdgcn_s_setprio(0);
    __syncthreads();

    for (int t = 1; t < 63; t += 2) {
        // odd tile t: compute B, emit A(t-1) in B's MFMA shadow
        stage(&bt[0][w * 512]);         // tile t+1 (even) -> buf 0
        __builtin_amdgcn_s_setprio(1);
        compute(accB, 1);
        screen_emit(accA, rmx, cur, hi, slist, ent_of(t - 1));
        __builtin_amdgcn_s_setprio(0);
        __syncthreads();
        // even tile t+1: compute A, emit B(t) in A's MFMA shadow
        stage(&bt[1][w * 512]);         // tile t+2 (odd) -> buf 1
        __builtin_amdgcn_s_setprio(1);
        compute(accA, 0);
        screen_emit(accB, rmx, cur, hi, slist, ent_of(t));
        __builtin_amdgcn_s_setprio(0);
        __syncthreads();
    }
    // tail: tile 63 (staged into buf 1 by the last loop iteration)
    __builtin_amdgcn_s_setprio(1);
    compute(accB, 1);
    screen_emit(accA, rmx, cur, hi, slist, ent_of(62));
    __builtin_amdgcn_s_setprio(0);
    screen_emit(accB, rmx, cur, hi, slist, ent_of(63));

    if (!hi) cnt[cidx] = cur;           // one writer per (row, quarter)
}

// Exact fp32 refine: gather <=176 stored (ent, bf16-dot) candidates from the 4
// quarter lists, filter by val >= finalmax - MARGIN (finalmax = max stored val;
// the record-setter always self-appends), then fp32 dots for the ~1-3 passing
// candidates. Serial fmaf order unchanged, so idx semantics are unchanged.
// Emits per-block loss partial: per-row loss = cn[bk] + bu (bu = zn - 2d of
// the winner). zn shifts all u_k equally -> argmin/tie semantics untouched.
__global__ __launch_bounds__(256) void k_refine(const float* __restrict__ zin,
                                                const float* __restrict__ ztf,
                                                const float* __restrict__ cb,
                                                const int2* __restrict__ surv,
                                                const int* __restrict__ cnt,
                                                int* __restrict__ idxi,
                                                float* __restrict__ idxf,
                                                const float* __restrict__ cn,
                                                float* __restrict__ lossp) {
    __shared__ float zr[4][256];
    __shared__ float lossw[4];
    int w = threadIdx.x >> 6, l = threadIdx.x & 63;
    int n = blockIdx.x * 4 + w;
    if (ztf) {
        const float* zrow = ztf + (size_t)n * 256;
#pragma unroll
        for (int i = 0; i < 4; ++i)
            zr[w][l + 64 * i] = zrow[l + 64 * i];          // coalesced
    } else {
        int b = n >> 12, s = n & 4095;
        const float* zb = zin + ((size_t)b << 20) + s;
#pragma unroll
        for (int i = 0; i < 4; ++i)
            zr[w][l + 64 * i] = zb[(size_t)(l + 64 * i) << 12];
    }
    __syncthreads();
    const float* z = zr[w];
    float zn = 0.f;
    for (int c = 0; c < 256; ++c) zn = fmaf(z[c], z[c], zn);

    int c0 = cnt[n * 4 + 0], c1 = cnt[n * 4 + 1];
    int c2 = cnt[n * 4 + 2], c3 = cnt[n * 4 + 3];
    int m = c0 + c1 + c2 + c3;
    bool ok = (c0 <= CAP_Q) && (c1 <= CAP_Q) && (c2 <= CAP_Q) && (c3 <= CAP_Q) && (m >= 1);
    float bu = 3.0e38f;
    int bk = 0x7fffffff;
    if (ok) {
        int myk[3]; float myv[3]; int nc = 0;
        float vmax = -3.0e38f;
        for (int i = l; i < m; i += 64) {
            int qq, s;
            if (i < c0)            { qq = 0; s = i; }
            else if (i < c0 + c1)  { qq = 1; s = i - c0; }
            else if (i < c0 + c1 + c2) { qq = 2; s = i - c0 - c1; }
            else                   { qq = 3; s = i - c0 - c1 - c2; }
            int2 kv = surv[(n * 4 + qq) * CAP_Q + s];
            myk[nc] = kv.x;
            myv[nc] = __int_as_float(kv.y);
            vmax = fmaxf(vmax, myv[nc]);
            ++nc;
        }
#pragma unroll
        for (int msk = 1; msk < 64; msk <<= 1)
            vmax = fmaxf(vmax, __shfl_xor(vmax, msk));
        float fthr = vmax - MARGIN;
        for (int jj = 0; jj < nc; ++jj) {
            if (myv[jj] >= fthr) {
                int k = myk[jj];
                const float* cr = cb + (size_t)k * 256;
                float d = 0.f;
                for (int c = 0; c < 256; c += 4) {
                    floatx4 wv = *(const floatx4*)(cr + c);
                    d = fmaf(z[c], wv[0], d);
                    d = fmaf(z[c + 1], wv[1], d);
                    d = fmaf(z[c + 2], wv[2], d);
                    d = fmaf(z[c + 3], wv[3], d);
                }
                float u = zn - 2.0f * d;
                if (u < bu || (u == bu && k < bk)) { bu = u; bk = k; }
            }
        }
    } else {
        // fallback: exact scan of all K with 4 independent chains (cold path)
        for (int kb = l; kb < K_ENT; kb += 256) {
            const float* p0 = cb + (size_t)(kb)       * 256;
            const float* p1 = cb + (size_t)(kb + 64)  * 256;
            const float* p2 = cb + (size_t)(kb + 128) * 256;
            const float* p3 = cb + (size_t)(kb + 192) * 256;
            float d0 = 0.f, d1 = 0.f, d2 = 0.f, d3 = 0.f;
            for (int c = 0; c < 256; c += 4) {
                floatx4 w0 = *(const floatx4*)(p0 + c);
                floatx4 w1 = *(const floatx4*)(p1 + c);
                floatx4 w2 = *(const floatx4*)(p2 + c);
                floatx4 w3 = *(const floatx4*)(p3 + c);
#pragma unroll
                for (int j = 0; j < 4; ++j) {
                    d0 = fmaf(z[c + j], w0[j], d0);
                    d1 = fmaf(z[c + j], w1[j], d1);
                    d2 = fmaf(z[c + j], w2[j], d2);
                    d3 = fmaf(z[c + j], w3[j], d3);
                }
            }
            float u0 = zn - 2.0f * d0, u1 = zn - 2.0f * d1;
            float u2 = zn - 2.0f * d2, u3 = zn - 2.0f * d3;
            // ascending k order preserves first-index tie-break
            if (u0 < bu) { bu = u0; bk = kb; }
            if (u1 < bu) { bu = u1; bk = kb + 64; }
            if (u2 < bu) { bu = u2; bk = kb + 128; }
            if (u3 < bu) { bu = u3; bk = kb + 192; }
        }
    }
#pragma unroll
    for (int msk = 1; msk < 64; msk <<= 1) {
        float ou = __shfl_xor(bu, msk);
        int   ok2 = __shfl_xor(bk, msk);
        if (ou < bu || (ou == bu && ok2 < bk)) { bu = ou; bk = ok2; }
    }
    if (l == 0) {
        idxi[n] = bk;
        idxf[n] = (float)bk;
        lossw[w] = bu + cn[bk];          // per-row loss = ||c_bk - z||^2
    }
    __syncthreads();
    if (threadIdx.x == 0)
        lossp[blockIdx.x] = (lossw[0] + lossw[1]) + (lossw[2] + lossw[3]);
}

// Gather z_q — ROUND 11: c-chunk parallel. Previously 512 blocks (2/CU) were
// latency-bound on random cb row reads (cb 8.4 MB > 4 MB per-XCD L2 -> L3
// round trips, too few waves to hide). Now each 64-row group is split across
// 4 blocks, one 64-wide c-chunk each: 2048 blocks (8/CU), identical total
// traffic (each block reads only its c-slice of the gathered rows), same
// write pattern. Block 0 additionally sums the 8192 refine loss partials.
__global__ __launch_bounds__(256) void k_gather(const float* __restrict__ cb,
                                                const int* __restrict__ idxi,
                                                const float* __restrict__ lossp,
                                                float* __restrict__ out) {
    __shared__ float tile[64][65];
    __shared__ int lk[64];
    __shared__ double dsum[4];
    int t = threadIdx.x;
    int blk = blockIdx.x;
    int ct = blk & 3;                   // c-chunk of this block
    int rg = blk >> 2;                  // 64-row group index [0, 512)
    int b = rg >> 6;
    int s0 = (rg & 63) << 6;
    int n0 = (b << 12) + s0;
    if (t < 64) lk[t] = idxi[n0 + t];
    __syncthreads();
    int wv = t >> 6, ln = t & 63;
    int c0 = ct << 6;
#pragma unroll
    for (int i = 0; i < 16; ++i) {
        int sl = (wv << 4) + i;
        tile[sl][ln] = cb[(size_t)lk[sl] * 256 + c0 + ln];   // 256 B coalesced
    }
    __syncthreads();
    float* ob = out + ((size_t)b << 20);
#pragma unroll
    for (int j = 0; j < 16; ++j) {
        int cl = (wv << 4) + j;
        ob[(size_t)(c0 + cl) * 4096 + s0 + ln] = tile[ln][cl];
    }
    if (blk == 0) {
        double s = 0.0;
        for (int i = t; i < 8192; i += 256) s += (double)lossp[i];
#pragma unroll
        for (int msk = 1; msk < 64; msk <<= 1) s += __shfl_xor(s, msk);
        if (ln == 0) dsum[wv] = s;
        __syncthreads();
        if (t == 0)
            out[LOSS_OFF] = (float)(2.0 * ((dsum[0] + dsum[1]) + (dsum[2] + dsum[3]))
                                    / 8388608.0);
    }
}

extern "C" void kernel_launch(void* const* d_in, const int* in_sizes, int n_in,
                              void* d_out, int out_size, void* d_ws, size_t ws_size,
                              hipStream_t stream) {
    (void)in_sizes; (void)n_in; (void)out_size;
    const float* z  = (const float*)d_in[0];
    const float* cb = (const float*)d_in[1];
    float* out = (float*)d_out;
    char* ws = (char*)d_ws;

    size_t off = 0;
    ushort_t* zsw  = (ushort_t*)(ws + off); off += 16777216;   // bf16 swizzled z
    ushort_t* cbsw = (ushort_t*)(ws + off); off += 4194304;    // bf16 swizzled codebook
    float* ztf = nullptr;
    const size_t ZTF_BYTES = 33554432;                          // fp32 transposed z
    const size_t SURV_BYTES = (size_t)N_ROWS * 4 * CAP_Q * 8;   // int2 lists (46 MB)
    const size_t TAIL = SURV_BYTES + 524288 + 131072 + 32768 + 32768;
    if (ws_size >= off + ZTF_BYTES + TAIL) { ztf = (float*)(ws + off); off += ZTF_BYTES; }
    int2* surv = (int2*)(ws + off); off += SURV_BYTES;
    int* cnt    = (int*)(ws + off); off += 524288;             // [n][quarter]
    int* idxi   = (int*)(ws + off); off += 131072;
    float* cn   = (float*)(ws + off); off += 32768;            // codebook sq-norms
    float* lossp = (float*)(ws + off); off += 32768;           // per-refine-block loss

    k_prep<<<3072, 256, 0, stream>>>(z, cb, zsw, cbsw, ztf, cn);
    k_screen<<<1024, 256, 0, stream>>>(zsw, cbsw, surv, cnt);
    k_refine<<<8192, 256, 0, stream>>>(z, ztf, cb, surv, cnt, idxi, out + IDX_OFF, cn, lossp);
    k_gather<<<2048, 256, 0, stream>>>(cb, idxi, lossp, out);
}